// Round 15
// baseline (191.534 us; speedup 1.0000x reference)
//
#include <hip/hip_runtime.h>
#include <hip/hip_bf16.h>
#include <stdint.h>

typedef __attribute__((ext_vector_type(4))) float  f32x4;
typedef __attribute__((ext_vector_type(8))) short  bf16x8;
typedef __attribute__((ext_vector_type(4))) float  float4v;
typedef __attribute__((ext_vector_type(4))) unsigned short u16x4;
typedef __attribute__((ext_vector_type(4))) uint32_t u32x4;
typedef __attribute__((ext_vector_type(2))) unsigned int uint2v;

typedef uint32_t u32_as1 __attribute__((address_space(1)));
typedef uint32_t u32_as3 __attribute__((address_space(3)));

#define CEXP_SCALE 0.045084221f   /* (1/32) * log2(e) */
#define INV_CEXP   22.180710f     /* 32 * ln(2) */

__device__ __forceinline__ void gload_lds16(const void* g, void* l) {
  __builtin_amdgcn_global_load_lds((const u32_as1*)g, (u32_as3*)l, 16, 0, 0);
}

__device__ __forceinline__ unsigned short f2bf(float f) {
  union { float f; uint32_t u; } v; v.f = f;
  uint32_t r = v.u + 0x7fffu + ((v.u >> 16) & 1u);
  return (unsigned short)(r >> 16);
}
__device__ __forceinline__ float bf2f(unsigned short u) {
  union { uint32_t u; float f; } v; v.u = ((uint32_t)u) << 16;
  return v.f;
}
// packed f32x2 -> bf16x2 (RNE), single VALU op
__device__ __forceinline__ uint32_t cvtpk_bf16(float lo, float hi) {
  uint32_t d;
  asm("v_cvt_pk_bf16_f32 %0, %1, %2" : "=v"(d) : "v"(lo), "v"(hi));
  return d;
}
// guaranteed single-instruction 2^x
__device__ __forceinline__ float exp2_hw(float x) {
  float r;
  asm("v_exp_f32 %0, %1" : "=v"(r) : "v"(x));
  return r;
}
// VALU-pipe lane broadcast pair: from value v, produce
//   lo = v[(base) + (l&15)], hi = v[(base) + 16 + (l&15)]
// where base = 0 (upper=false) or 32 (upper=true).
__device__ __forceinline__ void bcast_pair(uint32_t v, bool upper,
                                           uint32_t& lo, uint32_t& hi) {
  uint2v p32 = __builtin_amdgcn_permlane32_swap(v, v, false, false);
  uint32_t s = upper ? p32.y : p32.x;   // 32-half broadcast (compile-time select)
  uint2v p16 = __builtin_amdgcn_permlane16_swap(s, s, false, false);
  lo = p16.x;   // s[l & ~16]
  hi = p16.y;   // s[l | 16]
}

// ---------------- fused weight transposes f32 -> bf16: WT[z][n][k] = W_z[k][n] ----------------
__global__ __launch_bounds__(256) void wtrans4(const float* __restrict__ W0,
                                               const float* __restrict__ W1,
                                               const float* __restrict__ W2,
                                               const float* __restrict__ W3,
                                               unsigned short* __restrict__ WT, int D) {
  __shared__ float tile[32][33];
  const float* W = (blockIdx.z == 0) ? W0 : (blockIdx.z == 1) ? W1 : (blockIdx.z == 2) ? W2 : W3;
  unsigned short* WTz = WT + (size_t)blockIdx.z * D * D;
  int r0 = blockIdx.x * 32;
  int c0 = blockIdx.y * 32;
  int tc = threadIdx.x & 31;
  int tr = (threadIdx.x >> 5) * 4;
#pragma unroll
  for (int i = 0; i < 4; i++)
    tile[tr + i][tc] = W[(size_t)(r0 + tr + i) * D + c0 + tc];
  __syncthreads();
#pragma unroll
  for (int i = 0; i < 4; i++)
    WTz[(size_t)(c0 + tr + i) * D + r0 + tc] = f2bf(tile[tc][tr + i]);
}

// ---------------- fused Q + KV projection: f32-A double-buffered BK=32, XCD-remapped ----------------
// 768 blocks (256 Q + 512 KV), 48KB LDS -> 3 blocks/CU.
__global__ __launch_bounds__(256) void proj_gemm(
    const float* __restrict__ query, const float* __restrict__ key_,
    const unsigned short* __restrict__ WqT, const unsigned short* __restrict__ WkvT,
    const float* __restrict__ bq, const float* __restrict__ bk, const float* __restrict__ bv,
    unsigned short* __restrict__ Qs, unsigned short* __restrict__ Kp,
    unsigned short* __restrict__ Vt, int Nq, int D) {
  __shared__ __align__(16) float         AsmF[2][128 * 32];
  __shared__ __align__(16) unsigned short Bsm[2][128 * 32];
  int tid = threadIdx.x;
  int lane = tid & 63;
  int w = tid >> 6;
  int wr = (w >> 1) * 64;
  int wc = (w & 1) * 64;
  int r = lane & 15;
  int q4 = lane >> 4;

  int bid = blockIdx.x;
  bool isQ = bid < 256;
  const float* Af;
  const unsigned short* BT;
  int bm, bn;
  if (isQ) {
    int vid = ((bid & 7) << 5) | (bid >> 3);      // XCD k -> bn = k (weight panel/XCD)
    bm = (vid & 31) * 128; bn = (vid >> 5) * 128;
    Af = query; BT = WqT;
  } else {
    int b = bid - 256;
    int vid = ((b & 7) << 6) | (b >> 3);          // XCD k -> bn in {2k,2k+1}
    bm = (vid & 31) * 128; bn = (vid >> 5) * 128;
    Af = key_; BT = WkvT;
  }

  f32x4 acc[4][4] = {};

  auto STAGE = [&](int nb, int k0) {
#pragma unroll
    for (int i = 0; i < 4; i++) {
      int idx = i * 256 + tid;            // 0..1023 chunks of 16B (4 f32)
      int row = idx >> 3;                 // 8 chunks/row
      int cg = (idx & 7) ^ (row & 7);     // pre-swizzled source chunk
      gload_lds16(Af + (size_t)(bm + row) * 1024 + k0 + cg * 4, &AsmF[nb][idx * 4]);
    }
#pragma unroll
    for (int i = 0; i < 2; i++) {
      int idx = i * 256 + tid;            // 0..511 chunks (8 bf16)
      int row = idx >> 2;                 // 4 chunks/row
      int cg = (idx & 3) ^ (row & 3);
      gload_lds16(BT + (size_t)(bn + row) * 1024 + k0 + cg * 8, &Bsm[nb][idx * 8]);
    }
  };

  STAGE(0, 0);
  __syncthreads();

  int cur = 0;
  for (int t = 0; t < 32; ++t) {
    if (t + 1 < 32) STAGE(cur ^ 1, (t + 1) * 32);   // issue next-tile loads FIRST
    bf16x8 af[4], bfr[4];
    int c0 = q4 * 2;
    int x = r & 7;
#pragma unroll
    for (int mb = 0; mb < 4; mb++) {
      const float* rp = &AsmF[cur][(wr + mb * 16 + r) * 32];
      f32x4 a0 = *(const f32x4*)(rp + ((c0 ^ x) * 4));
      f32x4 a1 = *(const f32x4*)(rp + (((c0 + 1) ^ x) * 4));
      u32x4 tt = {cvtpk_bf16(a0.x, a0.y), cvtpk_bf16(a0.z, a0.w),
                  cvtpk_bf16(a1.x, a1.y), cvtpk_bf16(a1.z, a1.w)};
      af[mb] = __builtin_bit_cast(bf16x8, tt);
    }
    int chb = (q4 ^ (r & 3)) * 8;
#pragma unroll
    for (int nb = 0; nb < 4; nb++)
      bfr[nb] = *(const bf16x8*)&Bsm[cur][(wc + nb * 16 + r) * 32 + chb];
#pragma unroll
    for (int mb = 0; mb < 4; mb++)
#pragma unroll
      for (int nb = 0; nb < 4; nb++)
        acc[mb][nb] = __builtin_amdgcn_mfma_f32_16x16x32_bf16(af[mb], bfr[nb], acc[mb][nb], 0, 0, 0);
    __syncthreads();
    cur ^= 1;
  }

#pragma unroll
  for (int mb = 0; mb < 4; mb++) {
#pragma unroll
    for (int nb = 0; nb < 4; nb++) {
      int col = bn + wc + nb * 16 + r;
      if (isQ) {
        float bv2 = bq[col];
#pragma unroll
        for (int rr = 0; rr < 4; rr++) {
          int row = bm + wr + mb * 16 + q4 * 4 + rr;
          Qs[(size_t)row * 1024 + col] = f2bf((acc[mb][nb][rr] + bv2) * CEXP_SCALE);
        }
      } else if (col < 1024) {
        float bv2 = bk[col];
#pragma unroll
        for (int rr = 0; rr < 4; rr++) {
          int row = bm + wr + mb * 16 + q4 * 4 + rr;
          Kp[(size_t)row * 1024 + col] = f2bf(acc[mb][nb][rr] + bv2);
        }
      } else {
        int ccol = col - 1024;
        float bv2 = bv[ccol];
        u16x4 ov;
#pragma unroll
        for (int rr = 0; rr < 4; rr++)
          ov[rr] = f2bf(acc[mb][nb][rr] + bv2);
        int row0 = bm + wr + mb * 16 + q4 * 4;
        *(u16x4*)(Vt + (size_t)ccol * Nq + row0) = ov;
      }
    }
  }
}

// ---------------- FFN GEMM: double-buffered BK=64, XCD-remapped ----------------
__global__ __launch_bounds__(256) void ffn_gemm(
    const unsigned short* __restrict__ A, const unsigned short* __restrict__ WlT,
    const float* __restrict__ bl, unsigned short* __restrict__ C,
    const unsigned short* __restrict__ RES, int Nq, int D) {
  __shared__ __align__(16) unsigned short Asm[2][128 * 64];
  __shared__ __align__(16) unsigned short Bsm[2][128 * 64];
  int tid = threadIdx.x;
  int lane = tid & 63;
  int w = tid >> 6;
  int wr = (w >> 1) * 64;
  int wc = (w & 1) * 64;
  int bid = blockIdx.x;
  int vid = ((bid & 7) << 5) | (bid >> 3);   // XCD k -> bn = k
  int bm = (vid & 31) * 128;
  int bn = (vid >> 5) * 128;
  int r = lane & 15;
  int q4 = lane >> 4;

  f32x4 acc[4][4] = {};

  auto STAGE = [&](int nb, int k0) {
#pragma unroll
    for (int i = 0; i < 4; i++) {
      int idx = i * 256 + tid;
      int row = idx >> 3;
      int g = ((idx & 7) ^ (row & 7)) * 8;
      gload_lds16(A + (size_t)(bm + row) * D + k0 + g, &Asm[nb][idx * 8]);
      gload_lds16(WlT + (size_t)(bn + row) * D + k0 + g, &Bsm[nb][idx * 8]);
    }
  };

  STAGE(0, 0);
  __syncthreads();

  int cur = 0;
  const int NT = D >> 6;  // 16 K-steps
  for (int t = 0; t < NT; ++t) {
    if (t + 1 < NT) STAGE(cur ^ 1, (t + 1) * 64);
#pragma unroll
    for (int kk = 0; kk < 2; kk++) {
      int ch = ((kk * 4 + q4) ^ (r & 7)) * 8;
      bf16x8 af[4], bfr[4];
#pragma unroll
      for (int mb = 0; mb < 4; mb++)
        af[mb] = *(const bf16x8*)&Asm[cur][(wr + mb * 16 + r) * 64 + ch];
#pragma unroll
      for (int nb = 0; nb < 4; nb++)
        bfr[nb] = *(const bf16x8*)&Bsm[cur][(wc + nb * 16 + r) * 64 + ch];
#pragma unroll
      for (int mb = 0; mb < 4; mb++)
#pragma unroll
        for (int nb = 0; nb < 4; nb++)
          acc[mb][nb] = __builtin_amdgcn_mfma_f32_16x16x32_bf16(af[mb], bfr[nb], acc[mb][nb], 0, 0, 0);
    }
    __syncthreads();
    cur ^= 1;
  }

#pragma unroll
  for (int mb = 0; mb < 4; mb++) {
#pragma unroll
    for (int nb = 0; nb < 4; nb++) {
      int col = bn + wc + nb * 16 + r;
      float bv = bl[col];
#pragma unroll
      for (int rr = 0; rr < 4; rr++) {
        int row = bm + wr + mb * 16 + q4 * 4 + rr;
        float v = acc[mb][nb][rr] + bv;
        float res = bf2f(RES[(size_t)row * 1024 + col]);
        v = res + (v > 0.f ? v : 0.f);
        C[(size_t)row * 1024 + col] = f2bf(v);
      }
    }
  }
}

// ---------------- flash attention: LDS-staged K/V, swapped QK^T, VALU permlane P-repack ----------------
// R11 config (256 thr, grid 1024, z-split 2, lb(256,4)); ds_bpermute repack replaced by
// permlane32/16_swap (VALU pipe) -- removes ~8K LDS ops + their 8-way conflicts per CU.
__global__ __launch_bounds__(256, 4) void attn_kernel(
    const unsigned short* __restrict__ Qs,   // [Nq,1024] bf16, pre-scaled by scale*log2e
    const unsigned short* __restrict__ Kp,   // [Nk,1024] bf16
    const unsigned short* __restrict__ Vt,   // [1024,Nk] bf16 (V transposed)
    unsigned short* __restrict__ Opart,      // [2][Nq,1024] bf16 unnormalized
    float* __restrict__ Lpart,               // [2][16][Nq] f32 row sums
    int Nq, int Nk) {
  __shared__ __align__(16) unsigned short Ksm[2][4096];  // [buf][frag*512 + lane*8]
  __shared__ __align__(16) unsigned short Vsm[2][4096];
  const int Dm = 1024;
  int tid = threadIdx.x;
  int w = tid >> 6;
  int lane = tid & 63;
  int r = lane & 15;
  int q4 = lane >> 4;
  // XCD-contiguous remap: 1024 blocks, XCD k gets vids k*128..k*128+127 = 2 heads x 32 qb x 2 z
  int bid = blockIdx.x;
  int vid = ((bid & 7) << 7) + (bid >> 3);
  int h = vid >> 6;
  int qw = ((vid >> 1) & 31) * 128 + w * 32;
  int z = vid & 1;
  int k_beg = z * (Nk >> 1);
  const int NT = Nk >> 7;  // tiles of 64 keys over half the keys

  const unsigned short* Kb = Kp + h * 64;
  const unsigned short* Vb = Vt + (size_t)h * 64 * Nk;

  bool hi4 = (lane & 16) != 0;   // q4 odd -> P sources in upper 32 lanes

  bf16x8 qf[2][2];
#pragma unroll
  for (int mb = 0; mb < 2; mb++)
#pragma unroll
    for (int s = 0; s < 2; s++)
      qf[mb][s] = *(const bf16x8*)(Qs + (size_t)(qw + mb * 16 + r) * Dm + h * 64 + s * 32 + q4 * 8);

  // all-ones bf16 B-frag for MFMA row-sum
  bf16x8 ones;
#pragma unroll
  for (int i = 0; i < 8; i++) ones[i] = (short)0x3F80;

  const f32x4 czero = {0.f, 0.f, 0.f, 0.f};
  f32x4 acc[2][4] = {};
  f32x4 acc_s[2] = {};

  auto STAGE = [&](int nb, int key0) {
    if (w < 2) {
#pragma unroll
      for (int k = 0; k < 4; k++) {
        int j = w * 4 + k;            // 0..7
        int s = j >> 2, cb = j & 3;
        gload_lds16(Kb + (size_t)(key0 + cb * 16 + r) * Dm + s * 32 + q4 * 8,
                    &Ksm[nb][j * 512]);
      }
    } else {
#pragma unroll
      for (int k = 0; k < 4; k++) {
        int j = (w - 2) * 4 + k;      // 0..7
        int s = j >> 2, db = j & 3;
        gload_lds16(Vb + (size_t)(db * 16 + r) * Nk + key0 + s * 32 + q4 * 8,
                    &Vsm[nb][j * 512]);
      }
    }
  };

  STAGE(0, k_beg);
  __syncthreads();

  int cur = 0;
  for (int t = 0; t < NT; ++t) {
    if (t + 1 < NT) STAGE(cur ^ 1, k_beg + (t + 1) * 64);  // issue async loads FIRST

    // QK^T swapped: sacc[mb][cb] = S^T block (rows=keys, cols=q)
    bf16x8 kfr0[4], kfr1[4];
#pragma unroll
    for (int cb = 0; cb < 4; cb++) {
      kfr0[cb] = *(const bf16x8*)&Ksm[cur][(0 * 4 + cb) * 512 + lane * 8];
      kfr1[cb] = *(const bf16x8*)&Ksm[cur][(1 * 4 + cb) * 512 + lane * 8];
    }
    f32x4 sacc[2][4];
#pragma unroll
    for (int cb = 0; cb < 4; cb++)
#pragma unroll
      for (int mb = 0; mb < 2; mb++)
        sacc[mb][cb] = __builtin_amdgcn_mfma_f32_16x16x32_bf16(kfr0[cb], qf[mb][0], czero, 0, 0, 0);
#pragma unroll
    for (int cb = 0; cb < 4; cb++)
#pragma unroll
      for (int mb = 0; mb < 2; mb++)
        sacc[mb][cb] = __builtin_amdgcn_mfma_f32_16x16x32_bf16(kfr1[cb], qf[mb][1], sacc[mb][cb], 0, 0, 0);

    // exp + pack to bf16 pairs (row-sum handled by ones-MFMA below)
    uint32_t pk[2][4][2];
#pragma unroll
    for (int mb = 0; mb < 2; mb++)
#pragma unroll
      for (int cb = 0; cb < 4; cb++) {
        float p0 = exp2_hw(sacc[mb][cb][0]);
        float p1 = exp2_hw(sacc[mb][cb][1]);
        float p2 = exp2_hw(sacc[mb][cb][2]);
        float p3 = exp2_hw(sacc[mb][cb][3]);
        pk[mb][cb][0] = cvtpk_bf16(p0, p1);
        pk[mb][cb][1] = cvtpk_bf16(p2, p3);
      }

    // PV: repack P^T -> A-frag via permlane (VALU pipe), V frags from LDS; +ones-MFMA row-sums
#pragma unroll
    for (int s = 0; s < 2; s++) {
      bf16x8 pf[2];
#pragma unroll
      for (int mb = 0; mb < 2; mb++) {
        uint32_t ax0, bx0, ax1, bx1, ay0, by0, ay1, by1;
        bcast_pair(pk[mb][2 * s][0],     false, ax0, bx0);
        bcast_pair(pk[mb][2 * s][1],     false, ax1, bx1);
        bcast_pair(pk[mb][2 * s + 1][0], true,  ay0, by0);
        bcast_pair(pk[mb][2 * s + 1][1], true,  ay1, by1);
        uint32_t w0 = hi4 ? ay0 : ax0;
        uint32_t w1 = hi4 ? ay1 : ax1;
        uint32_t w2 = hi4 ? by0 : bx0;
        uint32_t w3 = hi4 ? by1 : bx1;
        u32x4 tmp = {w0, w1, w2, w3};
        pf[mb] = __builtin_bit_cast(bf16x8, tmp);
      }
      acc_s[0] = __builtin_amdgcn_mfma_f32_16x16x32_bf16(pf[0], ones, acc_s[0], 0, 0, 0);
      acc_s[1] = __builtin_amdgcn_mfma_f32_16x16x32_bf16(pf[1], ones, acc_s[1], 0, 0, 0);
#pragma unroll
      for (int db = 0; db < 4; db++) {
        bf16x8 vfx = *(const bf16x8*)&Vsm[cur][(s * 4 + db) * 512 + lane * 8];
        acc[0][db] = __builtin_amdgcn_mfma_f32_16x16x32_bf16(pf[0], vfx, acc[0][db], 0, 0, 0);
        acc[1][db] = __builtin_amdgcn_mfma_f32_16x16x32_bf16(pf[1], vfx, acc[1][db], 0, 0, 0);
      }
    }

    __syncthreads();
    cur ^= 1;
  }

  // write partials: acc_s D-layout row (q4*4+rr) matches the O-row this lane stores
  unsigned short* Op = Opart + (size_t)z * Nq * Dm;
#pragma unroll
  for (int mb = 0; mb < 2; mb++)
#pragma unroll
    for (int rr = 0; rr < 4; rr++) {
      int qrow = qw + mb * 16 + q4 * 4 + rr;
      if (r == 0)
        Lpart[(size_t)(z * 16 + h) * Nq + qrow] = acc_s[mb][rr];
#pragma unroll
      for (int db = 0; db < 4; db++) {
        int col = h * 64 + db * 16 + r;
        Op[(size_t)qrow * Dm + col] = f2bf(acc[mb][db][rr]);
      }
    }
}

// ---------------- combine splits + Q residual + LayerNorm1 (block per row) ----------------
__global__ __launch_bounds__(256) void combine_ln(
    const unsigned short* __restrict__ Qs,   // [Nq,1024] bf16 pre-scaled
    const unsigned short* __restrict__ Op,   // [2][Nq,1024] bf16
    const float* __restrict__ Lp,            // [2][16][Nq]
    const float* __restrict__ g, const float* __restrict__ b,
    unsigned short* __restrict__ out, int Nq) {
  int row = blockIdx.x;
  int tid = threadIdx.x;
  int h = tid >> 4;  // (tid*4)>>6
  size_t base = (size_t)row * 1024 + tid * 4;
  float linv = 1.0f / (Lp[(size_t)h * Nq + row] + Lp[(size_t)(16 + h) * Nq + row]);
  u16x4 qv = *(const u16x4*)(Qs + base);
  u16x4 a0 = *(const u16x4*)(Op + base);
  u16x4 a1 = *(const u16x4*)(Op + (size_t)Nq * 1024 + base);
  float x0 = bf2f(qv.x) * INV_CEXP + (bf2f(a0.x) + bf2f(a1.x)) * linv;
  float x1 = bf2f(qv.y) * INV_CEXP + (bf2f(a0.y) + bf2f(a1.y)) * linv;
  float x2 = bf2f(qv.z) * INV_CEXP + (bf2f(a0.z) + bf2f(a1.z)) * linv;
  float x3 = bf2f(qv.w) * INV_CEXP + (bf2f(a0.w) + bf2f(a1.w)) * linv;
  float s = x0 + x1 + x2 + x3;
  float s2 = x0 * x0 + x1 * x1 + x2 * x2 + x3 * x3;
#pragma unroll
  for (int m = 1; m < 64; m <<= 1) { s += __shfl_xor(s, m); s2 += __shfl_xor(s2, m); }
  __shared__ float red[8];
  int w = tid >> 6, lane = tid & 63;
  if (lane == 0) { red[w] = s; red[4 + w] = s2; }
  __syncthreads();
  s = red[0] + red[1] + red[2] + red[3];
  s2 = red[4] + red[5] + red[6] + red[7];
  float mean = s * (1.0f / 1024.0f);
  float var = s2 * (1.0f / 1024.0f) - mean * mean;
  float inv = rsqrtf(var + 1e-5f);
  float y0 = (x0 - mean) * inv * g[tid * 4 + 0] + b[tid * 4 + 0];
  float y1 = (x1 - mean) * inv * g[tid * 4 + 1] + b[tid * 4 + 1];
  float y2 = (x2 - mean) * inv * g[tid * 4 + 2] + b[tid * 4 + 2];
  float y3 = (x3 - mean) * inv * g[tid * 4 + 3] + b[tid * 4 + 3];
  u16x4 o = {f2bf(y0), f2bf(y1), f2bf(y2), f2bf(y3)};
  *(u16x4*)(out + base) = o;
}

// ---------------- LayerNorm (block per row, D=1024) ----------------
template <int OUTF32>
__global__ __launch_bounds__(256) void ln_kernel(
    const unsigned short* __restrict__ X,  // bf16 [N,D]
    const float* __restrict__ g, const float* __restrict__ b,
    void* __restrict__ outp, int D) {
  int row = blockIdx.x;
  int tid = threadIdx.x;
  const unsigned short* xr = X + (size_t)row * D;
  u16x4 xv = *(const u16x4*)(xr + tid * 4);
  float x0 = bf2f(xv.x), x1 = bf2f(xv.y), x2 = bf2f(xv.z), x3 = bf2f(xv.w);
  float s = x0 + x1 + x2 + x3;
  float s2 = x0 * x0 + x1 * x1 + x2 * x2 + x3 * x3;
#pragma unroll
  for (int m = 1; m < 64; m <<= 1) { s += __shfl_xor(s, m); s2 += __shfl_xor(s2, m); }
  __shared__ float red[8];
  int w = tid >> 6, lane = tid & 63;
  if (lane == 0) { red[w] = s; red[4 + w] = s2; }
  __syncthreads();
  s = red[0] + red[1] + red[2] + red[3];
  s2 = red[4] + red[5] + red[6] + red[7];
  float mean = s * (1.0f / 1024.0f);
  float var = s2 * (1.0f / 1024.0f) - mean * mean;
  float inv = rsqrtf(var + 1e-5f);
  float y0 = (x0 - mean) * inv * g[tid * 4 + 0] + b[tid * 4 + 0];
  float y1 = (x1 - mean) * inv * g[tid * 4 + 1] + b[tid * 4 + 1];
  float y2 = (x2 - mean) * inv * g[tid * 4 + 2] + b[tid * 4 + 2];
  float y3 = (x3 - mean) * inv * g[tid * 4 + 3] + b[tid * 4 + 3];
  if (OUTF32) {
    float4v o = {y0, y1, y2, y3};
    *(float4v*)((float*)outp + (size_t)row * D + tid * 4) = o;
  } else {
    u16x4 o = {f2bf(y0), f2bf(y1), f2bf(y2), f2bf(y3)};
    *(u16x4*)((unsigned short*)outp + (size_t)row * D + tid * 4) = o;
  }
}

extern "C" void kernel_launch(void* const* d_in, const int* in_sizes, int n_in,
                              void* d_out, int out_size, void* d_ws, size_t ws_size,
                              hipStream_t stream) {
  (void)in_sizes; (void)n_in; (void)out_size; (void)ws_size;
  const float* query = (const float*)d_in[0];
  const float* key_  = (const float*)d_in[1];
  const float* Wq = (const float*)d_in[2];
  const float* bq = (const float*)d_in[3];
  const float* Wk = (const float*)d_in[4];
  const float* bk = (const float*)d_in[5];
  const float* Wv = (const float*)d_in[6];
  const float* bv_ = (const float*)d_in[7];
  const float* g1 = (const float*)d_in[8];
  const float* b1 = (const float*)d_in[9];
  const float* Wl = (const float*)d_in[10];
  const float* bl = (const float*)d_in[11];
  const float* g2 = (const float*)d_in[12];
  const float* b2 = (const float*)d_in[13];
  float* out = (float*)d_out;

  const int Nq = 4096, Nk = 4096, D = 1024;
  const size_t MEl = (size_t)4096 * 1024;  // 4M elements
  const size_t DD = (size_t)D * D;

  unsigned short* w16 = (unsigned short*)d_ws;
  unsigned short* WqT = w16;                       // 1M el each; WqT..WlT contiguous
  unsigned short* WkT = WqT + DD;
  unsigned short* WvT = WkT + DD;                  // adjacent to WkT (fused KV GEMM, N=2048)
  unsigned short* WlT = WvT + DD;
  unsigned short* Qs  = w16 + 4 * DD;              // 4M el (pre-scaled Q projection)
  unsigned short* Kp  = Qs + MEl;
  unsigned short* Vt  = Kp + MEl;                  // [1024][4096] V^T (GEMM writes directly)
  unsigned short* Opart = Vt + MEl;                // [2][Nq,1024]
  unsigned short* out1  = Opart + 2 * MEl;
  float* Lpart = (float*)(out1 + MEl);             // 2*16*4096 f32
  unsigned short* out2  = Opart;                   // Opart dead after combine_ln

  wtrans4<<<dim3(32, 32, 4), 256, 0, stream>>>(Wq, Wk, Wv, Wl, WqT, D);

  proj_gemm<<<768, 256, 0, stream>>>(query, key_, WqT, WkT, bq, bk, bv_,
                                     Qs, Kp, Vt, Nq, D);

  attn_kernel<<<1024, 256, 0, stream>>>(Qs, Kp, Vt, Opart, Lpart, Nq, Nk);

  combine_ln<<<4096, 256, 0, stream>>>(Qs, Opart, Lpart, g1, b1, out1, Nq);
  ffn_gemm<<<256, 256, 0, stream>>>(out1, WlT, bl, out2, out1, Nq, D);
  ln_kernel<1><<<4096, 256, 0, stream>>>(out2, g2, b2, (void*)out, D);
}

// Round 16
// 171.060 us; speedup vs baseline: 1.1197x; 1.1197x over previous
//
#include <hip/hip_runtime.h>
#include <hip/hip_bf16.h>
#include <stdint.h>

typedef __attribute__((ext_vector_type(4))) float  f32x4;
typedef __attribute__((ext_vector_type(8))) short  bf16x8;
typedef __attribute__((ext_vector_type(4))) float  float4v;
typedef __attribute__((ext_vector_type(4))) unsigned short u16x4;
typedef __attribute__((ext_vector_type(4))) uint32_t u32x4;

typedef uint32_t u32_as1 __attribute__((address_space(1)));
typedef uint32_t u32_as3 __attribute__((address_space(3)));

#define CEXP_SCALE 0.045084221f   /* (1/32) * log2(e) */
#define INV_CEXP   22.180710f     /* 32 * ln(2) */

__device__ __forceinline__ void gload_lds16(const void* g, void* l) {
  __builtin_amdgcn_global_load_lds((const u32_as1*)g, (u32_as3*)l, 16, 0, 0);
}

__device__ __forceinline__ unsigned short f2bf(float f) {
  union { float f; uint32_t u; } v; v.f = f;
  uint32_t r = v.u + 0x7fffu + ((v.u >> 16) & 1u);
  return (unsigned short)(r >> 16);
}
__device__ __forceinline__ float bf2f(unsigned short u) {
  union { uint32_t u; float f; } v; v.u = ((uint32_t)u) << 16;
  return v.f;
}
// packed f32x2 -> bf16x2 (RNE), single VALU op
__device__ __forceinline__ uint32_t cvtpk_bf16(float lo, float hi) {
  uint32_t d;
  asm("v_cvt_pk_bf16_f32 %0, %1, %2" : "=v"(d) : "v"(lo), "v"(hi));
  return d;
}
// guaranteed single-instruction 2^x
__device__ __forceinline__ float exp2_hw(float x) {
  float r;
  asm("v_exp_f32 %0, %1" : "=v"(r) : "v"(x));
  return r;
}

// ---------------- fused weight transposes f32 -> bf16: WT[z][n][k] = W_z[k][n] ----------------
__global__ __launch_bounds__(256) void wtrans4(const float* __restrict__ W0,
                                               const float* __restrict__ W1,
                                               const float* __restrict__ W2,
                                               const float* __restrict__ W3,
                                               unsigned short* __restrict__ WT, int D) {
  __shared__ float tile[32][33];
  const float* W = (blockIdx.z == 0) ? W0 : (blockIdx.z == 1) ? W1 : (blockIdx.z == 2) ? W2 : W3;
  unsigned short* WTz = WT + (size_t)blockIdx.z * D * D;
  int r0 = blockIdx.x * 32;
  int c0 = blockIdx.y * 32;
  int tc = threadIdx.x & 31;
  int tr = (threadIdx.x >> 5) * 4;
#pragma unroll
  for (int i = 0; i < 4; i++)
    tile[tr + i][tc] = W[(size_t)(r0 + tr + i) * D + c0 + tc];
  __syncthreads();
#pragma unroll
  for (int i = 0; i < 4; i++)
    WTz[(size_t)(c0 + tr + i) * D + r0 + tc] = f2bf(tile[tc][tr + i]);
}

// ---------------- GEMM core (single-buffered): C[bm:+128, bn:+128] = A @ BT^T + bias ----------------
template <int AF32>
__device__ __forceinline__ void gemm_core(
    const void* __restrict__ Ain, const unsigned short* __restrict__ BT,
    const float* __restrict__ bias, const float* __restrict__ bias2,
    unsigned short* __restrict__ C, unsigned short* __restrict__ VtOut,
    const unsigned short* __restrict__ RES,
    int M, int K, int relu_res, float cscale, int bm, int bn,
    unsigned char* AsmRaw, unsigned short* Bsm) {
  int tid = threadIdx.x;
  int lane = tid & 63;
  int w = tid >> 6;
  int wr = (w >> 1) * 64;
  int wc = (w & 1) * 64;
  int r = lane & 15;
  int q4 = lane >> 4;

  f32x4 acc[4][4] = {};

  for (int k0 = 0; k0 < K; k0 += 64) {
    if (AF32) {
      const float* Af = (const float*)Ain;
#pragma unroll
      for (int i = 0; i < 8; i++) {
        int idx = i * 256 + tid;              // 0..2047 (16B chunks)
        int row = idx >> 4;                   // 0..127
        int cg = (idx & 15) ^ (row & 15);     // pre-swizzled source chunk
        gload_lds16(Af + (size_t)(bm + row) * K + k0 + cg * 4,
                    (float*)AsmRaw + idx * 4);
      }
    } else {
      const unsigned short* Ab = (const unsigned short*)Ain;
#pragma unroll
      for (int i = 0; i < 4; i++) {
        int idx = i * 256 + tid;              // 0..1023
        int row = idx >> 3;
        int g = ((idx & 7) ^ (row & 7)) * 8;
        gload_lds16(Ab + (size_t)(bm + row) * K + k0 + g,
                    (unsigned short*)AsmRaw + idx * 8);
      }
    }
#pragma unroll
    for (int i = 0; i < 4; i++) {
      int idx = i * 256 + tid;
      int row = idx >> 3;
      int g = ((idx & 7) ^ (row & 7)) * 8;
      gload_lds16(BT + (size_t)(bn + row) * K + k0 + g, &Bsm[idx * 8]);
    }
    __syncthreads();
#pragma unroll
    for (int kk = 0; kk < 2; kk++) {
      bf16x8 af[4], bfr[4];
      if (AF32) {
        const float* AsF = (const float*)AsmRaw;
        int c0 = kk * 8 + q4 * 2;
#pragma unroll
        for (int mb = 0; mb < 4; mb++) {
          int row = wr + mb * 16 + r;
          const float* rp = AsF + row * 64;
          int x = row & 15;
          f32x4 a0 = *(const f32x4*)(rp + ((c0 ^ x) * 4));
          f32x4 a1 = *(const f32x4*)(rp + (((c0 + 1) ^ x) * 4));
          u32x4 t = {cvtpk_bf16(a0.x, a0.y), cvtpk_bf16(a0.z, a0.w),
                     cvtpk_bf16(a1.x, a1.y), cvtpk_bf16(a1.z, a1.w)};
          af[mb] = __builtin_bit_cast(bf16x8, t);
        }
      } else {
        const unsigned short* AsB = (const unsigned short*)AsmRaw;
        int ch = ((kk * 4 + q4) ^ (r & 7)) * 8;
#pragma unroll
        for (int mb = 0; mb < 4; mb++)
          af[mb] = *(const bf16x8*)&AsB[(wr + mb * 16 + r) * 64 + ch];
      }
      int chb = ((kk * 4 + q4) ^ (r & 7)) * 8;
#pragma unroll
      for (int nb = 0; nb < 4; nb++)
        bfr[nb] = *(const bf16x8*)&Bsm[(wc + nb * 16 + r) * 64 + chb];
#pragma unroll
      for (int mb = 0; mb < 4; mb++)
#pragma unroll
        for (int nb = 0; nb < 4; nb++)
          acc[mb][nb] = __builtin_amdgcn_mfma_f32_16x16x32_bf16(af[mb], bfr[nb], acc[mb][nb], 0, 0, 0);
    }
    __syncthreads();
  }

#pragma unroll
  for (int mb = 0; mb < 4; mb++) {
#pragma unroll
    for (int nb = 0; nb < 4; nb++) {
      int col = bn + wc + nb * 16 + r;
      bool second = (VtOut != nullptr) && (col >= 1024);
      int ccol = second ? (col - 1024) : col;
      float bv = second ? bias2[ccol] : bias[ccol];
      if (second) {
        u16x4 ov;
#pragma unroll
        for (int rr = 0; rr < 4; rr++)
          ov[rr] = f2bf(acc[mb][nb][rr] + bv);
        int row0 = bm + wr + mb * 16 + q4 * 4;
        *(u16x4*)(VtOut + (size_t)ccol * M + row0) = ov;
      } else {
#pragma unroll
        for (int rr = 0; rr < 4; rr++) {
          int row = bm + wr + mb * 16 + q4 * 4 + rr;
          float v = acc[mb][nb][rr] + bv;
          if (relu_res) {
            float res = bf2f(RES[(size_t)row * 1024 + ccol]);
            v = res + (v > 0.f ? v : 0.f);
          }
          C[(size_t)row * 1024 + ccol] = f2bf(v * cscale);
        }
      }
    }
  }
}

// ---------------- fused Q + KV projection: 768 blocks, 3 blocks/CU ----------------
__global__ __launch_bounds__(256) void proj_gemm(
    const float* __restrict__ query, const float* __restrict__ key_,
    const unsigned short* __restrict__ WqT, const unsigned short* __restrict__ WkvT,
    const float* __restrict__ bq, const float* __restrict__ bk, const float* __restrict__ bv,
    unsigned short* __restrict__ Qs, unsigned short* __restrict__ Kp,
    unsigned short* __restrict__ Vt, int Nq, int D) {
  __shared__ __align__(16) unsigned char AsmRaw[128 * 64 * 4];
  __shared__ __align__(16) unsigned short Bsm[128 * 64];
  int bid = blockIdx.x;
  if (bid < 256) {
    gemm_core<1>(query, WqT, bq, nullptr, Qs, nullptr, nullptr,
                 Nq, D, 0, CEXP_SCALE, (bid & 31) * 128, (bid >> 5) * 128, AsmRaw, Bsm);
  } else {
    int b = bid - 256;
    gemm_core<1>(key_, WkvT, bk, bv, Kp, Vt, nullptr,
                 Nq, D, 0, 1.0f, (b & 31) * 128, (b >> 5) * 128, AsmRaw, Bsm);
  }
}

// ---------------- FFN GEMM: double-buffered LDS (2-phase), 1 barrier/K-step ----------------
__global__ __launch_bounds__(256) void ffn_gemm(
    const unsigned short* __restrict__ A, const unsigned short* __restrict__ WlT,
    const float* __restrict__ bl, unsigned short* __restrict__ C,
    const unsigned short* __restrict__ RES, int Nq, int D) {
  __shared__ __align__(16) unsigned short Asm[2][128 * 64];
  __shared__ __align__(16) unsigned short Bsm[2][128 * 64];
  int tid = threadIdx.x;
  int lane = tid & 63;
  int w = tid >> 6;
  int wr = (w >> 1) * 64;
  int wc = (w & 1) * 64;
  int bid = blockIdx.x;
  int bm = (bid & 31) * 128;
  int bn = (bid >> 5) * 128;
  int r = lane & 15;
  int q4 = lane >> 4;

  f32x4 acc[4][4] = {};

  auto STAGE = [&](int nb, int k0) {
#pragma unroll
    for (int i = 0; i < 4; i++) {
      int idx = i * 256 + tid;
      int row = idx >> 3;
      int g = ((idx & 7) ^ (row & 7)) * 8;
      gload_lds16(A + (size_t)(bm + row) * D + k0 + g, &Asm[nb][idx * 8]);
      gload_lds16(WlT + (size_t)(bn + row) * D + k0 + g, &Bsm[nb][idx * 8]);
    }
  };

  STAGE(0, 0);
  __syncthreads();

  int cur = 0;
  const int NT = D >> 6;  // 16 K-steps
  for (int t = 0; t < NT; ++t) {
    if (t + 1 < NT) STAGE(cur ^ 1, (t + 1) * 64);  // issue next-tile loads FIRST
#pragma unroll
    for (int kk = 0; kk < 2; kk++) {
      int ch = ((kk * 4 + q4) ^ (r & 7)) * 8;
      bf16x8 af[4], bfr[4];
#pragma unroll
      for (int mb = 0; mb < 4; mb++)
        af[mb] = *(const bf16x8*)&Asm[cur][(wr + mb * 16 + r) * 64 + ch];
#pragma unroll
      for (int nb = 0; nb < 4; nb++)
        bfr[nb] = *(const bf16x8*)&Bsm[cur][(wc + nb * 16 + r) * 64 + ch];
#pragma unroll
      for (int mb = 0; mb < 4; mb++)
#pragma unroll
        for (int nb = 0; nb < 4; nb++)
          acc[mb][nb] = __builtin_amdgcn_mfma_f32_16x16x32_bf16(af[mb], bfr[nb], acc[mb][nb], 0, 0, 0);
    }
    __syncthreads();  // drains next-tile staging; all waves done reading cur
    cur ^= 1;
  }

#pragma unroll
  for (int mb = 0; mb < 4; mb++) {
#pragma unroll
    for (int nb = 0; nb < 4; nb++) {
      int col = bn + wc + nb * 16 + r;
      float bv = bl[col];
#pragma unroll
      for (int rr = 0; rr < 4; rr++) {
        int row = bm + wr + mb * 16 + q4 * 4 + rr;
        float v = acc[mb][nb][rr] + bv;
        float res = bf2f(RES[(size_t)row * 1024 + col]);
        v = res + (v > 0.f ? v : 0.f);
        C[(size_t)row * 1024 + col] = f2bf(v);
      }
    }
  }
}

// ---------------- flash attention: LDS-staged K/V, swapped QK^T, in-register softmax, Nk-split ----------------
// Measured-best config (84.6 us): 256 threads, grid 1024, z-split 2, lb(256,4), bpermute repack.
__global__ __launch_bounds__(256, 4) void attn_kernel(
    const unsigned short* __restrict__ Qs,   // [Nq,1024] bf16, pre-scaled by scale*log2e
    const unsigned short* __restrict__ Kp,   // [Nk,1024] bf16
    const unsigned short* __restrict__ Vt,   // [1024,Nk] bf16 (V transposed)
    unsigned short* __restrict__ Opart,      // [2][Nq,1024] bf16 unnormalized
    float* __restrict__ Lpart,               // [2][16][Nq] f32 row sums
    int Nq, int Nk) {
  __shared__ __align__(16) unsigned short Ksm[2][4096];  // [buf][frag*512 + lane*8]
  __shared__ __align__(16) unsigned short Vsm[2][4096];
  const int Dm = 1024;
  int tid = threadIdx.x;
  int w = tid >> 6;
  int lane = tid & 63;
  int r = lane & 15;
  int q4 = lane >> 4;
  // XCD-contiguous remap: 1024 blocks, XCD k gets vids k*128..k*128+127 = 2 heads x 32 qb x 2 z
  int bid = blockIdx.x;
  int vid = ((bid & 7) << 7) + (bid >> 3);
  int h = vid >> 6;
  int qw = ((vid >> 1) & 31) * 128 + w * 32;
  int z = vid & 1;
  int k_beg = z * (Nk >> 1);
  const int NT = Nk >> 7;  // tiles of 64 keys over half the keys

  const unsigned short* Kb = Kp + h * 64;
  const unsigned short* Vb = Vt + (size_t)h * 64 * Nk;

  // source lanes for the P^T -> A-frag permutation
  int srcA = r + ((lane & 16) << 1);   // r + 32*(q4&1)
  int srcB = srcA + 16;
  bool hi_cb = (lane & 32) != 0;       // q4>>1

  bf16x8 qf[2][2];
#pragma unroll
  for (int mb = 0; mb < 2; mb++)
#pragma unroll
    for (int s = 0; s < 2; s++)
      qf[mb][s] = *(const bf16x8*)(Qs + (size_t)(qw + mb * 16 + r) * Dm + h * 64 + s * 32 + q4 * 8);

  // all-ones bf16 B-frag for MFMA row-sum
  bf16x8 ones;
#pragma unroll
  for (int i = 0; i < 8; i++) ones[i] = (short)0x3F80;

  const f32x4 czero = {0.f, 0.f, 0.f, 0.f};
  f32x4 acc[2][4] = {};
  f32x4 acc_s[2] = {};

  auto STAGE = [&](int nb, int key0) {
    if (w < 2) {
#pragma unroll
      for (int k = 0; k < 4; k++) {
        int j = w * 4 + k;            // 0..7
        int s = j >> 2, cb = j & 3;
        gload_lds16(Kb + (size_t)(key0 + cb * 16 + r) * Dm + s * 32 + q4 * 8,
                    &Ksm[nb][j * 512]);
      }
    } else {
#pragma unroll
      for (int k = 0; k < 4; k++) {
        int j = (w - 2) * 4 + k;      // 0..7
        int s = j >> 2, db = j & 3;
        gload_lds16(Vb + (size_t)(db * 16 + r) * Nk + key0 + s * 32 + q4 * 8,
                    &Vsm[nb][j * 512]);
      }
    }
  };

  STAGE(0, k_beg);
  __syncthreads();

  int cur = 0;
  for (int t = 0; t < NT; ++t) {
    if (t + 1 < NT) STAGE(cur ^ 1, k_beg + (t + 1) * 64);  // issue async loads FIRST

    // QK^T swapped: sacc[mb][cb] = S^T block (rows=keys, cols=q)
    bf16x8 kfr0[4], kfr1[4];
#pragma unroll
    for (int cb = 0; cb < 4; cb++) {
      kfr0[cb] = *(const bf16x8*)&Ksm[cur][(0 * 4 + cb) * 512 + lane * 8];
      kfr1[cb] = *(const bf16x8*)&Ksm[cur][(1 * 4 + cb) * 512 + lane * 8];
    }
    f32x4 sacc[2][4];
#pragma unroll
    for (int cb = 0; cb < 4; cb++)
#pragma unroll
      for (int mb = 0; mb < 2; mb++)
        sacc[mb][cb] = __builtin_amdgcn_mfma_f32_16x16x32_bf16(kfr0[cb], qf[mb][0], czero, 0, 0, 0);
#pragma unroll
    for (int cb = 0; cb < 4; cb++)
#pragma unroll
      for (int mb = 0; mb < 2; mb++)
        sacc[mb][cb] = __builtin_amdgcn_mfma_f32_16x16x32_bf16(kfr1[cb], qf[mb][1], sacc[mb][cb], 0, 0, 0);

    // exp + pack to bf16 pairs (row-sum handled by ones-MFMA below)
    uint32_t pk[2][4][2];
#pragma unroll
    for (int mb = 0; mb < 2; mb++)
#pragma unroll
      for (int cb = 0; cb < 4; cb++) {
        float p0 = exp2_hw(sacc[mb][cb][0]);
        float p1 = exp2_hw(sacc[mb][cb][1]);
        float p2 = exp2_hw(sacc[mb][cb][2]);
        float p3 = exp2_hw(sacc[mb][cb][3]);
        pk[mb][cb][0] = cvtpk_bf16(p0, p1);
        pk[mb][cb][1] = cvtpk_bf16(p2, p3);
      }

    // PV: repack P^T -> A-frag via shuffles, V frags from LDS; +ones-MFMA row-sums
#pragma unroll
    for (int s = 0; s < 2; s++) {
      bf16x8 pf[2];
#pragma unroll
      for (int mb = 0; mb < 2; mb++) {
        uint32_t s0 = hi_cb ? pk[mb][2 * s + 1][0] : pk[mb][2 * s][0];
        uint32_t s1 = hi_cb ? pk[mb][2 * s + 1][1] : pk[mb][2 * s][1];
        uint32_t w0 = (uint32_t)__shfl((int)s0, srcA);
        uint32_t w1 = (uint32_t)__shfl((int)s1, srcA);
        uint32_t w2 = (uint32_t)__shfl((int)s0, srcB);
        uint32_t w3 = (uint32_t)__shfl((int)s1, srcB);
        u32x4 tmp = {w0, w1, w2, w3};
        pf[mb] = __builtin_bit_cast(bf16x8, tmp);
      }
      acc_s[0] = __builtin_amdgcn_mfma_f32_16x16x32_bf16(pf[0], ones, acc_s[0], 0, 0, 0);
      acc_s[1] = __builtin_amdgcn_mfma_f32_16x16x32_bf16(pf[1], ones, acc_s[1], 0, 0, 0);
#pragma unroll
      for (int db = 0; db < 4; db++) {
        bf16x8 vfx = *(const bf16x8*)&Vsm[cur][(s * 4 + db) * 512 + lane * 8];
        acc[0][db] = __builtin_amdgcn_mfma_f32_16x16x32_bf16(pf[0], vfx, acc[0][db], 0, 0, 0);
        acc[1][db] = __builtin_amdgcn_mfma_f32_16x16x32_bf16(pf[1], vfx, acc[1][db], 0, 0, 0);
      }
    }

    __syncthreads();
    cur ^= 1;
  }

  // write partials: acc_s D-layout row (q4*4+rr) matches the O-row this lane stores
  unsigned short* Op = Opart + (size_t)z * Nq * Dm;
#pragma unroll
  for (int mb = 0; mb < 2; mb++)
#pragma unroll
    for (int rr = 0; rr < 4; rr++) {
      int qrow = qw + mb * 16 + q4 * 4 + rr;
      if (r == 0)
        Lpart[(size_t)(z * 16 + h) * Nq + qrow] = acc_s[mb][rr];
#pragma unroll
      for (int db = 0; db < 4; db++) {
        int col = h * 64 + db * 16 + r;
        Op[(size_t)qrow * Dm + col] = f2bf(acc[mb][db][rr]);
      }
    }
}

// ---------------- combine splits + Q residual + LayerNorm1 (block per row) ----------------
__global__ __launch_bounds__(256) void combine_ln(
    const unsigned short* __restrict__ Qs,   // [Nq,1024] bf16 pre-scaled
    const unsigned short* __restrict__ Op,   // [2][Nq,1024] bf16
    const float* __restrict__ Lp,            // [2][16][Nq]
    const float* __restrict__ g, const float* __restrict__ b,
    unsigned short* __restrict__ out, int Nq) {
  int row = blockIdx.x;
  int tid = threadIdx.x;
  int h = tid >> 4;  // (tid*4)>>6
  size_t base = (size_t)row * 1024 + tid * 4;
  float linv = 1.0f / (Lp[(size_t)h * Nq + row] + Lp[(size_t)(16 + h) * Nq + row]);
  u16x4 qv = *(const u16x4*)(Qs + base);
  u16x4 a0 = *(const u16x4*)(Op + base);
  u16x4 a1 = *(const u16x4*)(Op + (size_t)Nq * 1024 + base);
  float x0 = bf2f(qv.x) * INV_CEXP + (bf2f(a0.x) + bf2f(a1.x)) * linv;
  float x1 = bf2f(qv.y) * INV_CEXP + (bf2f(a0.y) + bf2f(a1.y)) * linv;
  float x2 = bf2f(qv.z) * INV_CEXP + (bf2f(a0.z) + bf2f(a1.z)) * linv;
  float x3 = bf2f(qv.w) * INV_CEXP + (bf2f(a0.w) + bf2f(a1.w)) * linv;
  float s = x0 + x1 + x2 + x3;
  float s2 = x0 * x0 + x1 * x1 + x2 * x2 + x3 * x3;
#pragma unroll
  for (int m = 1; m < 64; m <<= 1) { s += __shfl_xor(s, m); s2 += __shfl_xor(s2, m); }
  __shared__ float red[8];
  int w = tid >> 6, lane = tid & 63;
  if (lane == 0) { red[w] = s; red[4 + w] = s2; }
  __syncthreads();
  s = red[0] + red[1] + red[2] + red[3];
  s2 = red[4] + red[5] + red[6] + red[7];
  float mean = s * (1.0f / 1024.0f);
  float var = s2 * (1.0f / 1024.0f) - mean * mean;
  float inv = rsqrtf(var + 1e-5f);
  float y0 = (x0 - mean) * inv * g[tid * 4 + 0] + b[tid * 4 + 0];
  float y1 = (x1 - mean) * inv * g[tid * 4 + 1] + b[tid * 4 + 1];
  float y2 = (x2 - mean) * inv * g[tid * 4 + 2] + b[tid * 4 + 2];
  float y3 = (x3 - mean) * inv * g[tid * 4 + 3] + b[tid * 4 + 3];
  u16x4 o = {f2bf(y0), f2bf(y1), f2bf(y2), f2bf(y3)};
  *(u16x4*)(out + base) = o;
}

// ---------------- LayerNorm (block per row, D=1024) ----------------
template <int OUTF32>
__global__ __launch_bounds__(256) void ln_kernel(
    const unsigned short* __restrict__ X,  // bf16 [N,D]
    const float* __restrict__ g, const float* __restrict__ b,
    void* __restrict__ outp, int D) {
  int row = blockIdx.x;
  int tid = threadIdx.x;
  const unsigned short* xr = X + (size_t)row * D;
  u16x4 xv = *(const u16x4*)(xr + tid * 4);
  float x0 = bf2f(xv.x), x1 = bf2f(xv.y), x2 = bf2f(xv.z), x3 = bf2f(xv.w);
  float s = x0 + x1 + x2 + x3;
  float s2 = x0 * x0 + x1 * x1 + x2 * x2 + x3 * x3;
#pragma unroll
  for (int m = 1; m < 64; m <<= 1) { s += __shfl_xor(s, m); s2 += __shfl_xor(s2, m); }
  __shared__ float red[8];
  int w = tid >> 6, lane = tid & 63;
  if (lane == 0) { red[w] = s; red[4 + w] = s2; }
  __syncthreads();
  s = red[0] + red[1] + red[2] + red[3];
  s2 = red[4] + red[5] + red[6] + red[7];
  float mean = s * (1.0f / 1024.0f);
  float var = s2 * (1.0f / 1024.0f) - mean * mean;
  float inv = rsqrtf(var + 1e-5f);
  float y0 = (x0 - mean) * inv * g[tid * 4 + 0] + b[tid * 4 + 0];
  float y1 = (x1 - mean) * inv * g[tid * 4 + 1] + b[tid * 4 + 1];
  float y2 = (x2 - mean) * inv * g[tid * 4 + 2] + b[tid * 4 + 2];
  float y3 = (x3 - mean) * inv * g[tid * 4 + 3] + b[tid * 4 + 3];
  if (OUTF32) {
    float4v o = {y0, y1, y2, y3};
    *(float4v*)((float*)outp + (size_t)row * D + tid * 4) = o;
  } else {
    u16x4 o = {f2bf(y0), f2bf(y1), f2bf(y2), f2bf(y3)};
    *(u16x4*)((unsigned short*)outp + (size_t)row * D + tid * 4) = o;
  }
}

extern "C" void kernel_launch(void* const* d_in, const int* in_sizes, int n_in,
                              void* d_out, int out_size, void* d_ws, size_t ws_size,
                              hipStream_t stream) {
  (void)in_sizes; (void)n_in; (void)out_size; (void)ws_size;
  const float* query = (const float*)d_in[0];
  const float* key_  = (const float*)d_in[1];
  const float* Wq = (const float*)d_in[2];
  const float* bq = (const float*)d_in[3];
  const float* Wk = (const float*)d_in[4];
  const float* bk = (const float*)d_in[5];
  const float* Wv = (const float*)d_in[6];
  const float* bv_ = (const float*)d_in[7];
  const float* g1 = (const float*)d_in[8];
  const float* b1 = (const float*)d_in[9];
  const float* Wl = (const float*)d_in[10];
  const float* bl = (const float*)d_in[11];
  const float* g2 = (const float*)d_in[12];
  const float* b2 = (const float*)d_in[13];
  float* out = (float*)d_out;

  const int Nq = 4096, Nk = 4096, D = 1024;
  const size_t MEl = (size_t)4096 * 1024;  // 4M elements
  const size_t DD = (size_t)D * D;

  unsigned short* w16 = (unsigned short*)d_ws;
  unsigned short* WqT = w16;                       // 1M el each; WqT..WlT contiguous
  unsigned short* WkT = WqT + DD;
  unsigned short* WvT = WkT + DD;                  // adjacent to WkT (fused KV GEMM, N=2048)
  unsigned short* WlT = WvT + DD;
  unsigned short* Qs  = w16 + 4 * DD;              // 4M el (pre-scaled Q projection)
  unsigned short* Kp  = Qs + MEl;
  unsigned short* Vt  = Kp + MEl;                  // [1024][4096] V^T (GEMM writes directly)
  unsigned short* Opart = Vt + MEl;                // [2][Nq,1024]
  unsigned short* out1  = Opart + 2 * MEl;
  float* Lpart = (float*)(out1 + MEl);             // 2*16*4096 f32
  unsigned short* out2  = Opart;                   // Opart dead after combine_ln

  wtrans4<<<dim3(32, 32, 4), 256, 0, stream>>>(Wq, Wk, Wv, Wl, WqT, D);

  // fused Q + KV projections: 768 blocks = 3 blocks/CU
  proj_gemm<<<768, 256, 0, stream>>>(query, key_, WqT, WkT, bq, bk, bv_,
                                     Qs, Kp, Vt, Nq, D);

  attn_kernel<<<1024, 256, 0, stream>>>(Qs, Kp, Vt, Opart, Lpart, Nq, Nk);

  combine_ln<<<4096, 256, 0, stream>>>(Qs, Opart, Lpart, g1, b1, out1, Nq);
  ffn_gemm<<<256, 256, 0, stream>>>(out1, WlT, bl, out2, out1, Nq, D);
  ln_kernel<1><<<4096, 256, 0, stream>>>(out2, g2, b2, (void*)out, D);
}